// Round 4
// baseline (903.742 us; speedup 1.0000x reference)
//
#include <hip/hip_runtime.h>
#include <hip/hip_bf16.h>
#include <math.h>

typedef __attribute__((ext_vector_type(4))) float floatx4;
typedef __attribute__((ext_vector_type(8))) __bf16 bfloatx8;
typedef __attribute__((ext_vector_type(8))) unsigned short ushortx8;

static __device__ __forceinline__ unsigned short f2bf(float f) {
  __hip_bfloat16 h = __float2bfloat16(f);
  return *reinterpret_cast<unsigned short*>(&h);
}

static __device__ __forceinline__ void gload16(const void* g, void* l) {
  __builtin_amdgcn_global_load_lds(
      (const __attribute__((address_space(1))) unsigned int*)g,
      (__attribute__((address_space(3))) unsigned int*)l, 16, 0, 0);
}

#define S_BARRIER() __builtin_amdgcn_s_barrier()
#define WAIT_LGKM0() do { asm volatile("s_waitcnt lgkmcnt(0)" ::: "memory"); __builtin_amdgcn_sched_barrier(0); } while (0)
#define WAIT_VM(n)   do { asm volatile("s_waitcnt vmcnt(" #n ")" ::: "memory"); __builtin_amdgcn_sched_barrier(0); } while (0)

// ---------------- x: f32 -> bf16 ----------------
__global__ __launch_bounds__(256) void convert_x_kernel(const float4* __restrict__ in,
                                                        ushort4* __restrict__ out) {
  int i = blockIdx.x * 256 + threadIdx.x;
  float4 v = in[i];
  ushort4 o;
  o.x = f2bf(v.x); o.y = f2bf(v.y); o.z = f2bf(v.z); o.w = f2bf(v.w);
  out[i] = o;
}

// ------------- transpose + cast: out[c][r] = bf16(in[r][c]) -------------
__global__ __launch_bounds__(256) void transpose_bf16_kernel(const float* __restrict__ in,
                                                             unsigned short* __restrict__ out,
                                                             int rows, int cols) {
  __shared__ float tile[32][33];
  int c0 = blockIdx.x * 32, r0 = blockIdx.y * 32;
  int tx = threadIdx.x, ty = threadIdx.y;
#pragma unroll
  for (int j = 0; j < 32; j += 8)
    tile[ty + j][tx] = in[(size_t)(r0 + ty + j) * cols + c0 + tx];
  __syncthreads();
#pragma unroll
  for (int j = 0; j < 32; j += 8)
    out[(size_t)(c0 + ty + j) * rows + r0 + tx] = f2bf(tile[tx][ty + j]);
}

// ------------- lora_mid[m][r] = sum_k x[m][k] * a_down[idx][k][r] -------------
__global__ __launch_bounds__(256) void lora_mid_kernel(const float* __restrict__ x,
                                                       const float* __restrict__ a_down,
                                                       const int* __restrict__ idxp,
                                                       float* __restrict__ lmid) {
  __shared__ float ad[1024 * 9];
  const float* A = a_down + (size_t)(*idxp) * (1024 * 8);
  int t = threadIdx.x;
  for (int i = t; i < 8192; i += 256) ad[(i >> 3) * 9 + (i & 7)] = A[i];
  __syncthreads();
  int wid = t >> 6, lane = t & 63;
  int row = blockIdx.x * 4 + wid;
  const float* xr = x + (size_t)row * 1024;
  float acc[8] = {0.f, 0.f, 0.f, 0.f, 0.f, 0.f, 0.f, 0.f};
  for (int i = 0; i < 16; ++i) {
    int k = i * 64 + lane;
    float xv = xr[k];
#pragma unroll
    for (int r = 0; r < 8; ++r) acc[r] += xv * ad[k * 9 + r];
  }
#pragma unroll
  for (int off = 32; off > 0; off >>= 1) {
#pragma unroll
    for (int r = 0; r < 8; ++r) acc[r] += __shfl_xor(acc[r], off);
  }
  if (lane == 0) {
    *(float4*)(lmid + (size_t)row * 8) = make_float4(acc[0], acc[1], acc[2], acc[3]);
    *(float4*)(lmid + (size_t)row * 8 + 4) = make_float4(acc[4], acc[5], acc[6], acc[7]);
  }
}

// ================= 256x256 8-phase K-loop (BK=64, 8 waves, 128 KiB LDS dbuf) =================
// LDS buffer b at b*65536: A [256 rows][64 cols] bf16 at +0 (stage-halves h*16384 = rows
// h*128..h*128+127), B at +32768. Swizzle byte ^= ((row&7)<<4), applied identically on the
// pre-swizzled global source (gload_lds writes linearly) and on ds_read addrs (rule #21).
//
// Region quiet-windows (read phases: buf.A -> P1,P3 (wm-waves read their own 128-row half in
// BOTH); buf.B -> P1,P2,P4 (wn-waves likewise)):
//   buf0.A stageable after P3-close, buf0.B after P4-close, buf1.A after P7-close,
//   buf1.B after P8-close (i.e. next-iter P1+).
// Schedule (1 stage-group/phase, all issue points verified against quiet-windows):
//   P1: A1(T1)->b1   P2: B0(T1)->b1   P3: B1(T1)->b1   P4: A0(T0+2)->b0 +vmcnt(2)
//   P5: A1(T0+2)->b0 P6: B0(T0+2)->b0 P7: B1(T0+2)->b0 P8: A0(T1+2)->b1 +vmcnt(2)
// end-P4 vmcnt(2): outstanding 10 loads, drains {A0,A1,B0,B1}(T1) needed by P5-P8 (leaves
// P4's pair). end-P8 vmcnt(2): drains {A0..B1}(T0+2) needed by next P1-P4 (leaves P8's pair).
template <int LDA, int LDB, int NKT>
static __device__ __forceinline__ void kloop8(const unsigned short* __restrict__ A,
                                              const unsigned short* __restrict__ B,
                                              size_t m0, size_t n0, char* smem,
                                              floatx4 (&acc)[8][4]) {
  const int t = threadIdx.x;
  const int wid = t >> 6, lane = t & 63;
  const int wm = wid >> 2, wn = wid & 3;
  const int lr = lane & 15, kg = lane >> 4;
  const unsigned lxor = (unsigned)(lane & 7) << 4;
  const unsigned aRd = ((unsigned)(wm * 128 + lr) << 7) + ((unsigned)kg << 4);
  const unsigned bRd = 32768u + ((unsigned)(wn * 64 + lr) << 7) + ((unsigned)kg << 4);
  // staging: thread t owns linear LDS bytes t*16 (+8192 for second 64 rows); global source
  // col-block pre-swizzled by row&7 so that linear LDS write == swizzled layout
  const int srow = t >> 3;
  const int scol = ((t & 7) ^ ((t >> 3) & 7)) << 3;  // elements
  const unsigned short* sA = A + (m0 + (size_t)srow) * LDA + scol;
  const unsigned short* sB = B + (n0 + (size_t)srow) * LDB + scol;
  const unsigned ldsW = (unsigned)(wid << 10);

#define STG_A(tau, h, bufb)                                                            \
  do {                                                                                 \
    unsigned lo_ = (bufb) + (unsigned)(h)*16384u + ldsW;                               \
    gload16(sA + (size_t)((h)*128) * LDA + (size_t)(tau)*64, smem + lo_);              \
    gload16(sA + (size_t)((h)*128 + 64) * LDA + (size_t)(tau)*64, smem + lo_ + 8192);  \
  } while (0)
#define STG_B(tau, h, bufb)                                                            \
  do {                                                                                 \
    unsigned lo_ = (bufb) + 32768u + (unsigned)(h)*16384u + ldsW;                      \
    gload16(sB + (size_t)((h)*128) * LDB + (size_t)(tau)*64, smem + lo_);              \
    gload16(sB + (size_t)((h)*128 + 64) * LDB + (size_t)(tau)*64, smem + lo_ + 8192);  \
  } while (0)

  bfloatx8 af[4][2], bf[2][2];
#define LOAD_A(bufb, MH)                                                                          \
  do {                                                                                            \
    _Pragma("unroll") for (int mi = 0; mi < 4; ++mi)                                              \
        _Pragma("unroll") for (int ks = 0; ks < 2; ++ks)                                          \
            af[mi][ks] = *(const bfloatx8*)(smem +                                                \
                (((bufb) + aRd + (unsigned)(MH)*8192u + (unsigned)mi * 2048u + (unsigned)ks * 64u) ^ lxor)); \
  } while (0)
#define LOAD_B(bufb, NH)                                                                          \
  do {                                                                                            \
    _Pragma("unroll") for (int ni = 0; ni < 2; ++ni)                                              \
        _Pragma("unroll") for (int ks = 0; ks < 2; ++ks)                                          \
            bf[ni][ks] = *(const bfloatx8*)(smem +                                                \
                (((bufb) + bRd + (unsigned)(NH)*4096u + (unsigned)ni * 2048u + (unsigned)ks * 64u) ^ lxor)); \
  } while (0)
#define DO_MFMA(MH, NH)                                                                           \
  do {                                                                                            \
    __builtin_amdgcn_s_setprio(1);                                                                \
    _Pragma("unroll") for (int mi = 0; mi < 4; ++mi)                                              \
        _Pragma("unroll") for (int ni = 0; ni < 2; ++ni)                                          \
            _Pragma("unroll") for (int ks = 0; ks < 2; ++ks)                                      \
                acc[(MH)*4 + mi][(NH)*2 + ni] = __builtin_amdgcn_mfma_f32_16x16x32_bf16(          \
                    af[mi][ks], bf[ni][ks], acc[(MH)*4 + mi][(NH)*2 + ni], 0, 0, 0);              \
    __builtin_amdgcn_s_setprio(0);                                                                \
  } while (0)
#define PH(MH, NH, DOA, DOB, bufb, STAGE, VMW) \
  do {                                         \
    if (DOA) LOAD_A(bufb, MH);                 \
    if (DOB) LOAD_B(bufb, NH);                 \
    STAGE;                                     \
    S_BARRIER();                               \
    WAIT_LGKM0();                              \
    DO_MFMA(MH, NH);                           \
    VMW;                                       \
    S_BARRIER();                               \
  } while (0)

  // prologue: tile0 complete -> buf0; A0(tile1) -> buf1; drain tile0 (leave A0(1) in flight)
  STG_A(0, 0, 0u); STG_A(0, 1, 0u); STG_B(0, 0, 0u); STG_B(0, 1, 0u);
  STG_A(1, 0, 65536u);
  WAIT_VM(2);
  S_BARRIER();

  const int nit = NKT / 2;
#pragma unroll 1
  for (int it = 0; it < nit - 1; ++it) {
    const int t0 = 2 * it, t1 = 2 * it + 1;
    PH(0, 0, 1, 1, 0u, STG_A(t1, 1, 65536u), (void)0);
    PH(0, 1, 0, 1, 0u, STG_B(t1, 0, 65536u), (void)0);
    PH(1, 1, 1, 0, 0u, STG_B(t1, 1, 65536u), (void)0);
    PH(1, 0, 0, 1, 0u, STG_A(t0 + 2, 0, 0u), WAIT_VM(2));
    PH(0, 0, 1, 1, 65536u, STG_A(t0 + 2, 1, 0u), (void)0);
    PH(0, 1, 0, 1, 65536u, STG_B(t0 + 2, 0, 0u), (void)0);
    PH(1, 1, 1, 0, 65536u, STG_B(t0 + 2, 1, 0u), (void)0);
    PH(1, 0, 0, 1, 65536u, STG_A(t1 + 2, 0, 65536u), WAIT_VM(2));
  }
  {  // tail: tiles NKT-2 (buf0), NKT-1 (buf1); stage only A1/B0/B1 of last tile, then drain
    const int tl = NKT - 1;
    PH(0, 0, 1, 1, 0u, STG_A(tl, 1, 65536u), (void)0);
    PH(0, 1, 0, 1, 0u, STG_B(tl, 0, 65536u), (void)0);
    PH(1, 1, 1, 0, 0u, STG_B(tl, 1, 65536u), (void)0);
    PH(1, 0, 0, 1, 0u, (void)0, WAIT_VM(0));
    PH(0, 0, 1, 1, 65536u, (void)0, (void)0);
    PH(0, 1, 0, 1, 65536u, (void)0, (void)0);
    PH(1, 1, 1, 0, 65536u, (void)0, (void)0);
    PH(1, 0, 0, 1, 65536u, (void)0, (void)0);
  }
#undef PH
#undef DO_MFMA
#undef LOAD_B
#undef LOAD_A
#undef STG_B
#undef STG_A
}

// ------------- GEMM1: H = gelu(Xb @ W1T^T + b1), bf16 out. M=16384 N=4096 K=1024 -------------
__global__ __launch_bounds__(512, 2) void gemm1_8ph(const unsigned short* __restrict__ A,
                                                    const unsigned short* __restrict__ B,
                                                    const float* __restrict__ bias,
                                                    unsigned short* __restrict__ H) {
  extern __shared__ char smem[];
  const int nwg = 1024;
  int bid = blockIdx.x;
  int swz = (bid & 7) * (nwg / 8) + (bid >> 3);
  size_t m0 = (size_t)(swz / 16) * 256, n0 = (size_t)(swz % 16) * 256;
  floatx4 acc[8][4] = {};
  kloop8<1024, 1024, 16>(A, B, m0, n0, smem, acc);

  const int t = threadIdx.x;
  const int wid = t >> 6, lane = t & 63, wm = wid >> 2, wn = wid & 3, lr = lane & 15, kg = lane >> 4;
  float* sE = (float*)smem;  // [32][256]
  const int erow = t >> 4, ec0 = (t & 15) * 16;
#pragma unroll
  for (int mi = 0; mi < 8; ++mi) {
#pragma unroll
    for (int ni = 0; ni < 4; ++ni)
#pragma unroll
      for (int r = 0; r < 4; ++r)
        sE[(wm * 16 + kg * 4 + r) * 256 + wn * 64 + ni * 16 + lr] = acc[mi][ni][r];
    __syncthreads();
    const size_t gm = m0 + (size_t)(erow >> 4) * 128 + mi * 16 + (erow & 15);
    const int gc = (int)n0 + ec0;
    alignas(16) unsigned short pk[16];
#pragma unroll
    for (int i = 0; i < 16; ++i) {
      float v = sE[erow * 256 + ec0 + i] + bias[gc + i];
      float g = 0.5f * v * (1.0f + erff(v * 0.70710678118654752440f));
      pk[i] = f2bf(g);
    }
    *(ushortx8*)(H + gm * 4096 + gc) = *(const ushortx8*)&pk[0];
    *(ushortx8*)(H + gm * 4096 + gc + 8) = *(const ushortx8*)&pk[8];
    __syncthreads();
  }
}

// ------------- GEMM2: OUT = H @ W2T^T + b2 + lora, f32 out. M=16384 N=1024 K=4096 -------------
__global__ __launch_bounds__(512, 2) void gemm2_8ph(const unsigned short* __restrict__ A,
                                                    const unsigned short* __restrict__ B,
                                                    const float* __restrict__ bias,
                                                    const float* __restrict__ lmid,
                                                    const float* __restrict__ a_up,
                                                    const int* __restrict__ idxp,
                                                    float* __restrict__ OUT) {
  extern __shared__ char smem[];
  const int nwg = 256;
  int bid = blockIdx.x;
  int swz = (bid & 7) * (nwg / 8) + (bid >> 3);
  size_t m0 = (size_t)(swz / 4) * 256, n0 = (size_t)(swz % 4) * 256;
  floatx4 acc[8][4] = {};
  kloop8<4096, 4096, 64>(A, B, m0, n0, smem, acc);

  const int t = threadIdx.x;
  const int wid = t >> 6, lane = t & 63, wm = wid >> 2, wn = wid & 3, lr = lane & 15, kg = lane >> 4;
  float* sE = (float*)smem;  // [32][256]
  const float* aup = a_up + (size_t)(*idxp) * 8192;
  const int erow = t >> 4, ec0 = (t & 15) * 16;
#pragma unroll
  for (int mi = 0; mi < 8; ++mi) {
#pragma unroll
    for (int ni = 0; ni < 4; ++ni)
#pragma unroll
      for (int r = 0; r < 4; ++r)
        sE[(wm * 16 + kg * 4 + r) * 256 + wn * 64 + ni * 16 + lr] = acc[mi][ni][r];
    __syncthreads();
    const size_t gm = m0 + (size_t)(erow >> 4) * 128 + mi * 16 + (erow & 15);
    const int gc = (int)n0 + ec0;
    alignas(16) float lmv[8];
    *(float4*)&lmv[0] = *(const float4*)(lmid + gm * 8);
    *(float4*)&lmv[4] = *(const float4*)(lmid + gm * 8 + 4);
    alignas(16) float v[16];
#pragma unroll
    for (int i = 0; i < 16; ++i) v[i] = sE[erow * 256 + ec0 + i] + bias[gc + i];
#pragma unroll
    for (int r = 0; r < 8; ++r) {
      const float lw = lmv[r];
      const float* ar = aup + r * 1024 + gc;
#pragma unroll
      for (int i = 0; i < 16; ++i) v[i] += lw * ar[i];
    }
#pragma unroll
    for (int i = 0; i < 16; i += 4)
      *(float4*)(OUT + gm * 1024 + gc + i) = *(const float4*)&v[i];
    __syncthreads();
  }
}

extern "C" void kernel_launch(void* const* d_in, const int* in_sizes, int n_in,
                              void* d_out, int out_size, void* d_ws, size_t ws_size,
                              hipStream_t stream) {
  const float* x      = (const float*)d_in[0];
  const float* w1     = (const float*)d_in[1];
  const float* b1     = (const float*)d_in[2];
  const float* w2     = (const float*)d_in[3];
  const float* b2     = (const float*)d_in[4];
  const float* a_down = (const float*)d_in[5];
  const float* a_up   = (const float*)d_in[6];
  const int*   idx    = (const int*)d_in[7];
  float* out = (float*)d_out;

  char* ws = (char*)d_ws;
  unsigned short* Xb  = (unsigned short*)(ws);              // 16384x1024 bf16 = 32 MiB
  unsigned short* W1T = (unsigned short*)(ws + 33554432);   // 4096x1024 bf16 = 8 MiB
  unsigned short* W2T = (unsigned short*)(ws + 41943040);   // 1024x4096 bf16 = 8 MiB
  float*          LMID = (float*)(ws + 50331648);           // 16384x8 f32 = 0.5 MiB
  unsigned short* H   = (unsigned short*)(ws + 50855936);   // 16384x4096 bf16 = 128 MiB

  (void)hipFuncSetAttribute((const void*)gemm1_8ph, hipFuncAttributeMaxDynamicSharedMemorySize, 131072);
  (void)hipFuncSetAttribute((const void*)gemm2_8ph, hipFuncAttributeMaxDynamicSharedMemorySize, 131072);

  convert_x_kernel<<<16384, 256, 0, stream>>>((const float4*)x, (ushort4*)Xb);
  transpose_bf16_kernel<<<dim3(128, 32), dim3(32, 8), 0, stream>>>(w1, W1T, 1024, 4096);
  transpose_bf16_kernel<<<dim3(32, 128), dim3(32, 8), 0, stream>>>(w2, W2T, 4096, 1024);
  lora_mid_kernel<<<4096, 256, 0, stream>>>(x, a_down, idx, LMID);
  gemm1_8ph<<<1024, 512, 131072, stream>>>(Xb, W1T, b1, H);
  gemm2_8ph<<<256, 512, 131072, stream>>>(H, W2T, b2, LMID, a_up, idx, out);
}